// Round 1
// baseline (636.558 us; speedup 1.0000x reference)
//
#include <hip/hip_runtime.h>

#define NCH 32

// Factorized 1D sparse conv: out[p][d] = sum_{k,c} f[idx[k][p]][c] * W[k][c][d].
// Tap 1 (offset 0) is the identity map by construction -> own row, always valid.
// Taps 0/2 are random gathers; invalid (idx==n) handled branch-free by clamping
// the address to row 0 and scaling the gathered row by 0.
// Optionally fuses the BN per-channel sum / sum-of-squares reduction over the
// output (do_stats != 0): LDS block reduction (stride 33 -> conflict-free),
// one atomicAdd per channel per block.
__global__ __launch_bounds__(256) void conv1d_kernel(
    const float* __restrict__ f, const float* __restrict__ W,
    const int* __restrict__ idx, float* __restrict__ out, int n,
    float* __restrict__ stats, int do_stats)
{
    extern __shared__ float red[];   // [256][33] when do_stats

    int p = blockIdx.x * 256 + threadIdx.x;
    bool active = p < n;

    float acc[NCH];
#pragma unroll
    for (int ch = 0; ch < NCH; ++ch) acc[ch] = 0.f;

    if (active) {
        // issue both gather indices immediately (coalesced int loads)
        int i0 = idx[p];                       // tap 0: offset -1
        int i2 = idx[2 * (size_t)n + p];       // tap 2: offset +1
        float v0 = (i0 < n) ? 1.f : 0.f;
        float v2 = (i2 < n) ? 1.f : 0.f;
        const float4* r0 = (const float4*)(f + (size_t)(i0 < n ? i0 : 0) * NCH);
        const float4* r1 = (const float4*)(f + (size_t)p * NCH);          // identity tap
        const float4* r2 = (const float4*)(f + (size_t)(i2 < n ? i2 : 0) * NCH);

        // both random-gather rows fully in flight (16 float4 loads)
        float4 g0[8], g2[8];
#pragma unroll
        for (int c4 = 0; c4 < 8; ++c4) g0[c4] = r0[c4];
#pragma unroll
        for (int c4 = 0; c4 < 8; ++c4) g2[c4] = r2[c4];
#pragma unroll
        for (int c4 = 0; c4 < 8; ++c4) {
            g0[c4].x *= v0; g0[c4].y *= v0; g0[c4].z *= v0; g0[c4].w *= v0;
            g2[c4].x *= v2; g2[c4].y *= v2; g2[c4].z *= v2; g2[c4].w *= v2;
        }

        const float* w0 = W;
        const float* w1 = W + NCH * NCH;
        const float* w2 = W + 2 * NCH * NCH;
#pragma unroll
        for (int c4 = 0; c4 < 8; ++c4) {
            float4 b1 = r1[c4];                // own row streamed (coalesced, cache-hot)
            float a0[4] = {g0[c4].x, g0[c4].y, g0[c4].z, g0[c4].w};
            float a1[4] = {b1.x, b1.y, b1.z, b1.w};
            float a2[4] = {g2[c4].x, g2[c4].y, g2[c4].z, g2[c4].w};
#pragma unroll
            for (int j = 0; j < 4; ++j) {
                const float* wa = w0 + (size_t)(c4 * 4 + j) * NCH;
                const float* wb = w1 + (size_t)(c4 * 4 + j) * NCH;
                const float* wc = w2 + (size_t)(c4 * 4 + j) * NCH;
#pragma unroll
                for (int ch = 0; ch < NCH; ++ch) {
                    acc[ch] = fmaf(a0[j], wa[ch], acc[ch]);
                    acc[ch] = fmaf(a1[j], wb[ch], acc[ch]);
                    acc[ch] = fmaf(a2[j], wc[ch], acc[ch]);
                }
            }
        }

        float4* orow = (float4*)(out + (size_t)p * NCH);
#pragma unroll
        for (int c4 = 0; c4 < 8; ++c4) {
            float4 v;
            v.x = acc[c4 * 4 + 0];
            v.y = acc[c4 * 4 + 1];
            v.z = acc[c4 * 4 + 2];
            v.w = acc[c4 * 4 + 3];
            orow[c4] = v;
        }
    }

    if (do_stats) {
        // block-level per-channel sum & sumsq of acc (inactive threads hold zeros)
        float* myrow = red + threadIdx.x * 33;
#pragma unroll
        for (int ch = 0; ch < NCH; ++ch) myrow[ch] = acc[ch];
        __syncthreads();

        int ch = threadIdx.x & 31;
        int g  = threadIdx.x >> 5;             // 8 row-groups of 32
        float s = 0.f, q = 0.f;
#pragma unroll
        for (int r = 0; r < 32; ++r) {
            float v = red[(size_t)(g * 32 + r) * 33 + ch];
            s += v;
            q = fmaf(v, v, q);
        }
        __syncthreads();
        red[(size_t)g * 33 + ch] = s;
        red[(size_t)(8 + g) * 33 + ch] = q;
        __syncthreads();
        if (threadIdx.x < 32) {
            float S = 0.f, Q = 0.f;
#pragma unroll
            for (int gg = 0; gg < 8; ++gg) {
                S += red[(size_t)gg * 33 + ch];
                Q += red[(size_t)(8 + gg) * 33 + ch];
            }
            atomicAdd(&stats[ch], S);
            atomicAdd(&stats[NCH + ch], Q);
        }
    }
}

// BatchNorm (batch stats) + ReLU, in place on h [n,32]. One float4 per thread.
__global__ __launch_bounds__(256) void bn_relu_kernel(
    float* h, const float* __restrict__ stats,
    const float* __restrict__ gamma, const float* __restrict__ beta, int n)
{
    long tid = (long)blockIdx.x * 256 + threadIdx.x;
    long total4 = (long)n * NCH / 4;
    if (tid >= total4) return;

    int ch0 = ((int)(tid & 7)) * 4;
    float inv_n = 1.f / (float)n;

    float4 v = ((const float4*)h)[tid];
    float r[4] = {v.x, v.y, v.z, v.w};
#pragma unroll
    for (int j = 0; j < 4; ++j) {
        int ch = ch0 + j;
        float mean = stats[ch] * inv_n;
        float var = stats[NCH + ch] * inv_n - mean * mean;
        float scale = gamma[ch] * rsqrtf(var + 1e-5f);
        float shift = beta[ch] - mean * scale;
        float o = fmaf(r[j], scale, shift);
        r[j] = o > 0.f ? o : 0.f;
    }
    float4 o4;
    o4.x = r[0]; o4.y = r[1]; o4.z = r[2]; o4.w = r[3];
    ((float4*)h)[tid] = o4;
}

extern "C" void kernel_launch(void* const* d_in, const int* in_sizes, int n_in,
                              void* d_out, int out_size, void* d_ws, size_t ws_size,
                              hipStream_t stream)
{
    const float* feats = (const float*)d_in[0];
    const float* W1    = (const float*)d_in[1];
    const float* W2    = (const float*)d_in[2];
    const float* W3    = (const float*)d_in[3];
    const float* gamma = (const float*)d_in[4];
    const float* beta  = (const float*)d_in[5];
    const int*   nbr   = (const int*)d_in[6];   // [3 axes][3 taps][n]

    int n = in_sizes[0] / NCH;

    float* hout = (float*)d_out;                 // h1, then h3, then final out
    float* h2   = (float*)d_ws;                  // n*32 floats
    float* stats = h2 + (size_t)n * NCH;         // 64 floats

    int cblocks = (n + 255) / 256;
    size_t red_bytes = 256 * 33 * sizeof(float);

    // conv1: axis 2 (z), feats -> d_out
    conv1d_kernel<<<cblocks, 256, 0, stream>>>(feats, W1, nbr + (size_t)2 * 3 * n,
                                               hout, n, nullptr, 0);
    // conv2: axis 1 (y), d_out -> ws
    conv1d_kernel<<<cblocks, 256, 0, stream>>>(hout, W2, nbr + (size_t)1 * 3 * n,
                                               h2, n, nullptr, 0);

    // zero BN accumulators before conv3 (which fuses the stats reduction)
    hipMemsetAsync(stats, 0, 2 * NCH * sizeof(float), stream);

    // conv3: axis 0 (x), ws -> d_out, with fused per-channel sum/sumsq
    conv1d_kernel<<<cblocks, 256, red_bytes, stream>>>(h2, W3, nbr + (size_t)0 * 3 * n,
                                                       hout, n, stats, 1);

    // BN + ReLU in place
    long total4 = (long)n * NCH / 4;
    int nblocks = (int)((total4 + 255) / 256);
    bn_relu_kernel<<<nblocks, 256, 0, stream>>>(hout, stats, gamma, beta, n);
}

// Round 2
// 452.070 us; speedup vs baseline: 1.4081x; 1.4081x over previous
//
#include <hip/hip_runtime.h>

#define NCH 32

typedef __attribute__((ext_vector_type(8))) __bf16 bf16x8;
typedef __attribute__((ext_vector_type(4))) float  f32x4;

// Split 8 fp32 values into bf16 hi + bf16 lo (residual) fragments.
// ah*bh + al*bh + ah*bl reconstructs the fp32 product to ~2^-16 relative.
static __device__ __forceinline__ void split8(const float* x, bf16x8& hi, bf16x8& lo)
{
#pragma unroll
    for (int e = 0; e < 8; ++e) {
        __bf16 h = (__bf16)x[e];
        hi[e] = h;
        lo[e] = (__bf16)(x[e] - (float)h);
    }
}

static __device__ __forceinline__ void mfma3(
    const bf16x8& ah, const bf16x8& al,
    const bf16x8& wh, const bf16x8& wl, f32x4& acc)
{
    acc = __builtin_amdgcn_mfma_f32_16x16x32_bf16(ah, wh, acc, 0, 0, 0);
    acc = __builtin_amdgcn_mfma_f32_16x16x32_bf16(al, wh, acc, 0, 0, 0);
    acc = __builtin_amdgcn_mfma_f32_16x16x32_bf16(ah, wl, acc, 0, 0, 0);
}

// Factorized 1D sparse conv as MFMA GEMM over 16-point tiles.
// A fragment (16x32, K=channels): lane holds f[row = tb + (lane&15)][c0..c0+7],
//   c0 = (lane>>4)*8.  Invalid rows zeroed (missing neighbor / tail).
// B fragment (32x16): lane holds W[k][c0..c0+7][d = (lane&15) + 16*half].
// C/D: lane holds out[tb + (lane>>4)*4 + r][(lane&15) + 16*half], r=0..3.
// Tap 1 is the identity map (offset 0) -> own row, no index load.
// Taps 0/2: wave-uniform skip when no row in the tile has that neighbor
// (p_valid ~6% -> whole-tile skip prob ~37%).
// do_stats: fused per-channel sum/sumsq (channel == lane&15 in C layout),
// block LDS combine, 64 atomicAdds per block.
__global__ __launch_bounds__(256) void conv_mfma_kernel(
    const float* __restrict__ f, const float* __restrict__ W,
    const int* __restrict__ idx, float* __restrict__ out, int n,
    float* __restrict__ stats, int do_stats)
{
    __shared__ float red[4][4][16];

    const int lane = threadIdx.x & 63;
    const int wv   = threadIdx.x >> 6;
    const int r16  = lane & 15;
    const int g    = lane >> 4;
    const int c0   = g * 8;

    // B fragments: 3 taps x 2 output halves, hi/lo split (held in VGPRs).
    bf16x8 bh[3][2], bl[3][2];
#pragma unroll
    for (int k = 0; k < 3; ++k) {
#pragma unroll
        for (int h = 0; h < 2; ++h) {
            float w8[8];
#pragma unroll
            for (int e = 0; e < 8; ++e)
                w8[e] = W[k * NCH * NCH + (c0 + e) * NCH + (h * 16 + r16)];
            split8(w8, bh[k][h], bl[k][h]);
        }
    }

    const int ntiles = (n + 15) >> 4;
    const int nw = gridDim.x * 4;
    float s0 = 0.f, q0 = 0.f, s1 = 0.f, q1 = 0.f;

    for (int tile = blockIdx.x * 4 + wv; tile < ntiles; tile += nw) {
        const int tb = tile << 4;
        f32x4 a0 = {0.f, 0.f, 0.f, 0.f};
        f32x4 a1 = {0.f, 0.f, 0.f, 0.f};

        const int  p   = tb + r16;
        const bool pin = (p < n);

        // ---- tap 1: identity (own row) ----
        {
            const float4* rp = (const float4*)(f + (size_t)(pin ? p : 0) * NCH + c0);
            float4 x0 = rp[0];
            float4 x1 = rp[1];
            float m = pin ? 1.f : 0.f;
            float x[8] = {x0.x * m, x0.y * m, x0.z * m, x0.w * m,
                          x1.x * m, x1.y * m, x1.z * m, x1.w * m};
            bf16x8 ah, al;
            split8(x, ah, al);
            mfma3(ah, al, bh[1][0], bl[1][0], a0);
            mfma3(ah, al, bh[1][1], bl[1][1], a1);
        }

        // ---- taps 0 and 2: random gathers ----
#pragma unroll
        for (int t = 0; t < 2; ++t) {
            const int k = t * 2;
            int  i = idx[(size_t)k * n + (pin ? p : 0)];
            bool v = pin && (i < n);
            if (__any(v)) {
                const float4* rp = (const float4*)(f + (size_t)(v ? i : 0) * NCH + c0);
                float4 x0 = rp[0];
                float4 x1 = rp[1];
                float m = v ? 1.f : 0.f;
                float x[8] = {x0.x * m, x0.y * m, x0.z * m, x0.w * m,
                              x1.x * m, x1.y * m, x1.z * m, x1.w * m};
                bf16x8 ah, al;
                split8(x, ah, al);
                mfma3(ah, al, bh[k][0], bl[k][0], a0);
                mfma3(ah, al, bh[k][1], bl[k][1], a1);
            }
        }

        // ---- store C: row = tb + g*4 + r, col = r16 / r16+16 ----
#pragma unroll
        for (int r = 0; r < 4; ++r) {
            int prow = tb + g * 4 + r;
            if (prow < n) {
                float* o = out + (size_t)prow * NCH + r16;
                o[0]  = a0[r];
                o[16] = a1[r];
            }
        }

        if (do_stats) {
#pragma unroll
            for (int r = 0; r < 4; ++r) {
                s0 += a0[r]; q0 = fmaf(a0[r], a0[r], q0);
                s1 += a1[r]; q1 = fmaf(a1[r], a1[r], q1);
            }
        }
    }

    if (do_stats) {
        // lanes with the same (lane&15) hold the same channel: xor-16/32 reduce
        s0 += __shfl_xor(s0, 16); s0 += __shfl_xor(s0, 32);
        q0 += __shfl_xor(q0, 16); q0 += __shfl_xor(q0, 32);
        s1 += __shfl_xor(s1, 16); s1 += __shfl_xor(s1, 32);
        q1 += __shfl_xor(q1, 16); q1 += __shfl_xor(q1, 32);
        if (lane < 16) {
            red[wv][0][r16] = s0;
            red[wv][1][r16] = q0;
            red[wv][2][r16] = s1;
            red[wv][3][r16] = q1;
        }
        __syncthreads();
        if (threadIdx.x < 64) {
            int vsel = threadIdx.x >> 4;   // 0:s lo, 1:q lo, 2:s hi, 3:q hi
            int ch   = threadIdx.x & 15;
            float t = red[0][vsel][ch] + red[1][vsel][ch] +
                      red[2][vsel][ch] + red[3][vsel][ch];
            int channel = (vsel & 2) ? (ch + 16) : ch;
            atomicAdd(stats + ((vsel & 1) ? NCH : 0) + channel, t);
        }
    }
}

// BatchNorm (batch stats) + ReLU, in place on h [n,32]. One float4 per thread.
__global__ __launch_bounds__(256) void bn_relu_kernel(
    float* h, const float* __restrict__ stats,
    const float* __restrict__ gamma, const float* __restrict__ beta, int n)
{
    long tid = (long)blockIdx.x * 256 + threadIdx.x;
    long total4 = (long)n * NCH / 4;
    if (tid >= total4) return;

    int ch0 = ((int)(tid & 7)) * 4;
    float inv_n = 1.f / (float)n;

    float4 v = ((const float4*)h)[tid];
    float r[4] = {v.x, v.y, v.z, v.w};
#pragma unroll
    for (int j = 0; j < 4; ++j) {
        int ch = ch0 + j;
        float mean = stats[ch] * inv_n;
        float var = stats[NCH + ch] * inv_n - mean * mean;
        float scale = gamma[ch] * rsqrtf(var + 1e-5f);
        float shift = beta[ch] - mean * scale;
        float o = fmaf(r[j], scale, shift);
        r[j] = o > 0.f ? o : 0.f;
    }
    float4 o4;
    o4.x = r[0]; o4.y = r[1]; o4.z = r[2]; o4.w = r[3];
    ((float4*)h)[tid] = o4;
}

extern "C" void kernel_launch(void* const* d_in, const int* in_sizes, int n_in,
                              void* d_out, int out_size, void* d_ws, size_t ws_size,
                              hipStream_t stream)
{
    const float* feats = (const float*)d_in[0];
    const float* W1    = (const float*)d_in[1];
    const float* W2    = (const float*)d_in[2];
    const float* W3    = (const float*)d_in[3];
    const float* gamma = (const float*)d_in[4];
    const float* beta  = (const float*)d_in[5];
    const int*   nbr   = (const int*)d_in[6];   // [3 axes][3 taps][n]

    int n = in_sizes[0] / NCH;

    float* hout  = (float*)d_out;                // h1, then h3, then final out
    float* h2    = (float*)d_ws;                 // n*32 floats
    float* stats = h2 + (size_t)n * NCH;         // 64 floats

    const int cblocks = 1024;                    // 4 waves/block, grid-stride tiles

    // conv1: axis 2 (z), feats -> d_out
    conv_mfma_kernel<<<cblocks, 256, 0, stream>>>(feats, W1, nbr + (size_t)2 * 3 * n,
                                                  hout, n, nullptr, 0);
    // conv2: axis 1 (y), d_out -> ws
    conv_mfma_kernel<<<cblocks, 256, 0, stream>>>(hout, W2, nbr + (size_t)1 * 3 * n,
                                                  h2, n, nullptr, 0);

    // zero BN accumulators before conv3 (which fuses the stats reduction)
    hipMemsetAsync(stats, 0, 2 * NCH * sizeof(float), stream);

    // conv3: axis 0 (x), ws -> d_out, with fused per-channel sum/sumsq
    conv_mfma_kernel<<<cblocks, 256, 0, stream>>>(h2, W3, nbr + (size_t)0 * 3 * n,
                                                  hout, n, stats, 1);

    // BN + ReLU in place
    long total4 = (long)n * NCH / 4;
    int nblocks = (int)((total4 + 255) / 256);
    bn_relu_kernel<<<nblocks, 256, 0, stream>>>(hout, stats, gamma, beta, n);
}